// Round 13
// baseline (452.723 us; speedup 1.0000x reference)
//
#include <hip/hip_runtime.h>

typedef unsigned short u16;
typedef __attribute__((ext_vector_type(4))) u16 u16x4;
typedef __attribute__((ext_vector_type(8))) u16 u16x8;
typedef __attribute__((ext_vector_type(8))) _Float16 f16x8;
typedef __attribute__((ext_vector_type(4))) float f32x4;

__device__ __forceinline__ u16 f2h(float x) {
    _Float16 h = (_Float16)x;
    return __builtin_bit_cast(u16, h);
}
__device__ __forceinline__ float h2f(u16 u) {
    return (float)__builtin_bit_cast(_Float16, u);
}

__device__ __forceinline__ void gl_lds16(const void* g, void* l) {
    __builtin_amdgcn_global_load_lds(
        (const __attribute__((address_space(1))) void*)g,
        (__attribute__((address_space(3))) void*)l, 16, 0, 0);
}

// ===== fp16 GEMM, 128x128 tile + dispersed count (R12 — UNCHANGED) =====
__global__ __launch_bounds__(256) void gemm_mfma128_kernel(
    const u16* __restrict__ A, int lda,
    const u16* __restrict__ B, int ldb,
    const float* __restrict__ biasF, const float* __restrict__ biasB,
    u16* __restrict__ CbA, u16* __restrict__ CbB,
    const float* __restrict__ avec, float* __restrict__ scoreOut,
    const int* __restrict__ cV, const int* __restrict__ cE,
    int* __restrict__ ecnt, int* __restrict__ ncnt,
    int* __restrict__ rankE, int* __restrict__ rankN, int tNnz,
    int nCnt, int sStride,
    int M, int Nc, int ncSplit, int K, int nrb, int ncb)
{
    int g0 = blockIdx.x;
    int g = g0;
    if (nCnt > 0) {
        int nc1 = (g0 + 1) / sStride;
        int cIdx = nc1 - 1;
        if (((g0 + 1) % sStride == 0) && cIdx < nCnt) {
            // ---- dedicated count block (8 entries/thread) ----
            int k0 = (cIdx * 256 + (int)threadIdx.x) * 8;
            if (k0 >= tNnz) return;
            int kmax = min(tNnz - k0, 8);
            int vv[8], ee[8], rE[8], rN[8];
            if (kmax == 8) {
                int4 a = *(const int4*)(cV + k0), b = *(const int4*)(cV + k0 + 4);
                int4 c = *(const int4*)(cE + k0), d = *(const int4*)(cE + k0 + 4);
                vv[0]=a.x; vv[1]=a.y; vv[2]=a.z; vv[3]=a.w; vv[4]=b.x; vv[5]=b.y; vv[6]=b.z; vv[7]=b.w;
                ee[0]=c.x; ee[1]=c.y; ee[2]=c.z; ee[3]=c.w; ee[4]=d.x; ee[5]=d.y; ee[6]=d.z; ee[7]=d.w;
            } else {
                for (int q = 0; q < kmax; ++q) { vv[q] = cV[k0 + q]; ee[q] = cE[k0 + q]; }
            }
            for (int q = 0; q < kmax; ++q) rE[q] = atomicAdd(&ecnt[ee[q]], 1);
            for (int q = 0; q < kmax; ++q) rN[q] = atomicAdd(&ncnt[vv[q]], 1);
            if (kmax == 8) {
                int4 r0, r1;
                r0.x=rE[0]; r0.y=rE[1]; r0.z=rE[2]; r0.w=rE[3];
                r1.x=rE[4]; r1.y=rE[5]; r1.z=rE[6]; r1.w=rE[7];
                *(int4*)(rankE + k0) = r0;
                *(int4*)(rankE + k0 + 4) = r1;
                r0.x=rN[0]; r0.y=rN[1]; r0.z=rN[2]; r0.w=rN[3];
                r1.x=rN[4]; r1.y=rN[5]; r1.z=rN[6]; r1.w=rN[7];
                *(int4*)(rankN + k0) = r0;
                *(int4*)(rankN + k0 + 4) = r1;
            } else {
                for (int q = 0; q < kmax; ++q) { rankE[k0 + q] = rE[q]; rankN[k0 + q] = rN[q]; }
            }
            return;
        }
        g = g0 - min(nc1, nCnt);
    }

    int xcd = g & 7;
    int slot = g >> 3;
    int rbi = slot / ncb;
    int cb = slot - rbi * ncb;
    int rb = xcd + 8 * rbi;
    if (rb >= nrb) return;

    __shared__ __align__(16) u16 lds[16384];   // 32 KB: A 2x8192B, B 2x8192B
    u16* sA0 = lds;
    u16* sA1 = lds + 4096;
    u16* sB0 = lds + 8192;
    u16* sB1 = lds + 12288;

    int tid = threadIdx.x;
    int wave = tid >> 6, lane = tid & 63;
    int row0 = rb * 128, col0 = cb * 128;

    long gA[2], gB[2];
    int sOff[2];
#pragma unroll
    for (int r = 0; r < 2; ++r) {
        int trow = r * 64 + wave * 16 + (lane >> 2);
        int chunk = (lane & 3) ^ ((trow >> 2) & 3);
        int arow = min(row0 + trow, M - 1);
        gA[r] = (long)arow * lda + chunk * 8;
        gB[r] = (long)(col0 + trow) * ldb + chunk * 8;
        sOff[r] = (r * 64 + wave * 16) * 32;
    }

    int m16 = lane & 15, quad = lane >> 4;
    int offA[4], offB[4];
#pragma unroll
    for (int i = 0; i < 4; ++i) {
        int ra = (wave & 1) * 64 + i * 16 + m16;
        offA[i] = ra * 32 + ((quad ^ ((ra >> 2) & 3)) * 8);
    }
#pragma unroll
    for (int j = 0; j < 4; ++j) {
        int rbx = (wave >> 1) * 64 + j * 16 + m16;
        offB[j] = rbx * 32 + ((quad ^ ((rbx >> 2) & 3)) * 8);
    }

    f32x4 acc[4][4];
#pragma unroll
    for (int i = 0; i < 4; ++i)
#pragma unroll
        for (int j = 0; j < 4; ++j) {
            f32x4 z = {0.f, 0.f, 0.f, 0.f};
            acc[i][j] = z;
        }

    int nkb = K >> 6;   // BK = 64
    for (int kb = 0; kb < nkb; ++kb) {
#pragma unroll
        for (int r = 0; r < 2; ++r) {
            gl_lds16(A + gA[r], sA0 + sOff[r]);
            gl_lds16(A + gA[r] + 32, sA1 + sOff[r]);
            gl_lds16(B + gB[r], sB0 + sOff[r]);
            gl_lds16(B + gB[r] + 32, sB1 + sOff[r]);
        }
        __syncthreads();
        {
            f16x8 av[4], bv[4];
#pragma unroll
            for (int i = 0; i < 4; ++i) av[i] = *(const f16x8*)(sA0 + offA[i]);
#pragma unroll
            for (int j = 0; j < 4; ++j) bv[j] = *(const f16x8*)(sB0 + offB[j]);
#pragma unroll
            for (int i = 0; i < 4; ++i)
#pragma unroll
                for (int j = 0; j < 4; ++j)
                    acc[i][j] = __builtin_amdgcn_mfma_f32_16x16x32_f16(av[i], bv[j], acc[i][j], 0, 0, 0);
        }
        {
            f16x8 av[4], bv[4];
#pragma unroll
            for (int i = 0; i < 4; ++i) av[i] = *(const f16x8*)(sA1 + offA[i]);
#pragma unroll
            for (int j = 0; j < 4; ++j) bv[j] = *(const f16x8*)(sB1 + offB[j]);
#pragma unroll
            for (int i = 0; i < 4; ++i)
#pragma unroll
                for (int j = 0; j < 4; ++j)
                    acc[i][j] = __builtin_amdgcn_mfma_f32_16x16x32_f16(av[i], bv[j], acc[i][j], 0, 0, 0);
        }
        __syncthreads();
#pragma unroll
        for (int r = 0; r < 2; ++r) { gA[r] += 64; gB[r] += 64; }
    }

    // ---- epilogue: two 64x32 LDS-transpose passes staged in regs, then one
    //      contiguous 128B store burst per row ----
    int rbase = (wave & 1) * 64, cbase = (wave >> 1) * 64;
    float bj[4];
#pragma unroll
    for (int j = 0; j < 4; ++j) {
        int col = col0 + cbase + j * 16 + m16;
        bj[j] = (col >= ncSplit) ? biasB[col - ncSplit] : biasF[col];
    }
    bool isB = (col0 >= ncSplit);            // 128-aligned splits: tile-uniform
    u16* Cp = isB ? CbB : CbA;
    int stride = isB ? (Nc - ncSplit) : ncSplit;
    int ccb = (col0 + cbase) - (isB ? ncSplit : 0);
    bool doScore = (scoreOut != nullptr) && isB;
    int row = row0 + rbase + lane;
    u16* wlds = lds + wave * 2560;           // 64 rows x 40 u16 per wave
    u16x8 creg[2][4];
#pragma unroll
    for (int h = 0; h < 2; ++h) {
        __syncthreads();
#pragma unroll
        for (int jj = 0; jj < 2; ++jj) {
            int j = h * 2 + jj;
#pragma unroll
            for (int i = 0; i < 4; ++i)
#pragma unroll
                for (int rr = 0; rr < 4; ++rr) {
                    int lr = i * 16 + quad * 4 + rr;
                    int lc = jj * 16 + m16;
                    int seg = (lc >> 3) ^ ((lr >> 2) & 3);
                    wlds[lr * 40 + seg * 8 + (lc & 7)] = f2h(acc[i][j][rr] + bj[j]);
                }
        }
        __syncthreads();
#pragma unroll
        for (int s = 0; s < 4; ++s) {
            int sseg = s ^ ((lane >> 2) & 3);
            creg[h][s] = *(const u16x8*)(wlds + lane * 40 + sseg * 8);
        }
    }
    if (row < M) {
        u16* dst = Cp + (size_t)row * stride + ccb;
        float sp = 0.f;
#pragma unroll
        for (int h = 0; h < 2; ++h)
#pragma unroll
            for (int s = 0; s < 4; ++s) {
                *(u16x8*)(dst + h * 32 + s * 8) = creg[h][s];
                if (doScore) {
#pragma unroll
                    for (int q = 0; q < 8; ++q)
                        sp += h2f(creg[h][s][q]) * avec[ccb + h * 32 + s * 8 + q];
                }
            }
        if (doScore) atomicAdd(scoreOut + row, sp);
    }
}

// ===== fp16 GEMM, 128x64 tile (R6 verbatim — UNCHANGED) =====
__global__ __launch_bounds__(256) void gemm_mfma64_kernel(
    const u16* __restrict__ A, int lda,
    const u16* __restrict__ B, int ldb,
    const float* __restrict__ biasF, const float* __restrict__ biasB,
    u16* __restrict__ CbA, u16* __restrict__ CbB,
    const float* __restrict__ avec, float* __restrict__ scoreOut,
    int M, int Nc, int ncSplit, int K, int nrb, int ncb)
{
    int g = blockIdx.x;
    int xcd = g & 7;
    int slot = g >> 3;
    int rbi = slot / ncb;
    int cb = slot - rbi * ncb;
    int rb = xcd + 8 * rbi;
    if (rb >= nrb) return;

    __shared__ __align__(16) u16 lds[12288];   // 24 KB: A 2x4096, B 2x2048
    u16* sA0 = lds;
    u16* sA1 = lds + 4096;
    u16* sB0 = lds + 8192;
    u16* sB1 = lds + 10240;

    int tid = threadIdx.x;
    int wave = tid >> 6, lane = tid & 63;
    int row0 = rb * 128, col0 = cb * 64;

    long gA[2];
    int sOffA[2];
#pragma unroll
    for (int r = 0; r < 2; ++r) {
        int trow = r * 64 + wave * 16 + (lane >> 2);
        int chunk = (lane & 3) ^ ((trow >> 2) & 3);
        int arow = min(row0 + trow, M - 1);
        gA[r] = (long)arow * lda + chunk * 8;
        sOffA[r] = (r * 64 + wave * 16) * 32;
    }
    int trowB = wave * 16 + (lane >> 2);
    int chunkB = (lane & 3) ^ ((trowB >> 2) & 3);
    long gB = (long)(col0 + trowB) * ldb + chunkB * 8;
    int sOffB = (wave * 16) * 32;

    int m16 = lane & 15, quad = lane >> 4;
    int offA[4], offB[2];
#pragma unroll
    for (int i = 0; i < 4; ++i) {
        int ra = (wave & 1) * 64 + i * 16 + m16;
        offA[i] = ra * 32 + ((quad ^ ((ra >> 2) & 3)) * 8);
    }
#pragma unroll
    for (int j = 0; j < 2; ++j) {
        int rbx = (wave >> 1) * 32 + j * 16 + m16;
        offB[j] = rbx * 32 + ((quad ^ ((rbx >> 2) & 3)) * 8);
    }

    f32x4 acc[4][2];
#pragma unroll
    for (int i = 0; i < 4; ++i)
#pragma unroll
        for (int j = 0; j < 2; ++j) {
            f32x4 z = {0.f, 0.f, 0.f, 0.f};
            acc[i][j] = z;
        }

    int nkb = K >> 6;   // BK = 64
    for (int kb = 0; kb < nkb; ++kb) {
#pragma unroll
        for (int r = 0; r < 2; ++r) {
            gl_lds16(A + gA[r], sA0 + sOffA[r]);
            gl_lds16(A + gA[r] + 32, sA1 + sOffA[r]);
        }
        gl_lds16(B + gB, sB0 + sOffB);
        gl_lds16(B + gB + 32, sB1 + sOffB);
        __syncthreads();
        {
            f16x8 av[4], bv[2];
#pragma unroll
            for (int i = 0; i < 4; ++i) av[i] = *(const f16x8*)(sA0 + offA[i]);
#pragma unroll
            for (int j = 0; j < 2; ++j) bv[j] = *(const f16x8*)(sB0 + offB[j]);
#pragma unroll
            for (int i = 0; i < 4; ++i)
#pragma unroll
                for (int j = 0; j < 2; ++j)
                    acc[i][j] = __builtin_amdgcn_mfma_f32_16x16x32_f16(av[i], bv[j], acc[i][j], 0, 0, 0);
        }
        {
            f16x8 av[4], bv[2];
#pragma unroll
            for (int i = 0; i < 4; ++i) av[i] = *(const f16x8*)(sA1 + offA[i]);
#pragma unroll
            for (int j = 0; j < 2; ++j) bv[j] = *(const f16x8*)(sB1 + offB[j]);
#pragma unroll
            for (int i = 0; i < 4; ++i)
#pragma unroll
                for (int j = 0; j < 2; ++j)
                    acc[i][j] = __builtin_amdgcn_mfma_f32_16x16x32_f16(av[i], bv[j], acc[i][j], 0, 0, 0);
        }
        __syncthreads();
#pragma unroll
        for (int r = 0; r < 2; ++r) gA[r] += 64;
        gB += 64;
    }

    // ---- epilogue: per-wave LDS transpose (64 rows x 32 cols), 16B stores ----
    int rbase = (wave & 1) * 64, cbase = (wave >> 1) * 32;
    float bj[2];
#pragma unroll
    for (int j = 0; j < 2; ++j) {
        int col = col0 + cbase + j * 16 + m16;
        bj[j] = (col >= ncSplit) ? biasB[col - ncSplit] : biasF[col];
    }
    u16* wlds = lds + wave * 2560;   // 64 rows x 40 u16
    __syncthreads();
#pragma unroll
    for (int j = 0; j < 2; ++j)
#pragma unroll
        for (int i = 0; i < 4; ++i)
#pragma unroll
            for (int rr = 0; rr < 4; ++rr) {
                int lr = i * 16 + quad * 4 + rr;
                int lc = j * 16 + m16;
                int seg = (lc >> 3) ^ ((lr >> 2) & 3);
                wlds[lr * 40 + seg * 8 + (lc & 7)] = f2h(acc[i][j][rr] + bj[j]);
            }
    __syncthreads();
    {
        int colbase = col0 + cbase;
        bool isB = (colbase >= ncSplit);
        u16* Cp = isB ? CbB : CbA;
        int stride = isB ? (Nc - ncSplit) : ncSplit;
        int cc = isB ? (colbase - ncSplit) : colbase;
        bool doScore = (scoreOut != nullptr) && isB;
        int row = row0 + rbase + lane;
        if (row < M) {
            float sp = 0.f;
#pragma unroll
            for (int s = 0; s < 4; ++s) {
                int sseg = s ^ ((lane >> 2) & 3);
                u16x8 vv = *(const u16x8*)(wlds + lane * 40 + sseg * 8);
                *(u16x8*)(Cp + (size_t)row * stride + cc + s * 8) = vv;
                if (doScore) {
#pragma unroll
                    for (int q = 0; q < 8; ++q)
                        sp += h2f(vv[q]) * avec[cc + s * 8 + q];
                }
            }
            if (doScore) atomicAdd(scoreOut + row, sp);
        }
    }
}

// ====== fused prep: zero-tail + input casts + weight casts (no atomics) ======
struct WJob { const float* W; u16* Wt; int K; int ncShift; };
struct WJobs { WJob j[7]; };

__global__ void prep_fused_kernel(
    int* __restrict__ zbuf, int zN4, int nbZero,      // zero zN4 int4's
    const float* __restrict__ X, u16* __restrict__ Abuf, int n4x,
    const float* __restrict__ S, u16* __restrict__ Ae, int nS, int nbCast,
    WJobs jobs)
{
    int b = blockIdx.x;
    if (b < nbZero) {
        int id = b * 256 + (int)threadIdx.x;
        if (id < zN4) ((int4*)zbuf)[id] = make_int4(0, 0, 0, 0);
        return;
    }
    if (b < nbZero + nbCast) {
        int id = (b - nbZero) * 256 + (int)threadIdx.x;
        if (id < n4x) {
            float4 x = ((const float4*)X)[id];
            u16x4 h;
            h.x = f2h(x.x); h.y = f2h(x.y); h.z = f2h(x.z); h.w = f2h(x.w);
            *(u16x4*)(Abuf + (size_t)id * 4) = h;
        } else {
            int i = id - n4x;
            if (i < nS) {
                int e = i >> 6, c = i & 63;
                Ae[(size_t)e * 320 + 256 + c] = f2h(S[i]);
            }
        }
        return;
    }
    int bb = b - nbZero - nbCast;
    int job = bb / 320, rem = bb - job * 320;
    WJob jb = jobs.j[job];
    int Nc = 1 << jb.ncShift;
    int idx = rem * 256 + (int)threadIdx.x;
    if (idx >= jb.K * Nc) return;
    int k = idx >> jb.ncShift, n = idx & (Nc - 1);
    jb.Wt[(size_t)n * jb.K + k] = f2h(jb.W[idx]);
}

// =============== dual-array scans ===============
__global__ __launch_bounds__(256) void scan_part1_dual(
    const int* __restrict__ cntE, int* __restrict__ offE, int* __restrict__ psumE, int nE, int nbE,
    const int* __restrict__ cntN, int* __restrict__ offN, int* __restrict__ psumN, int nN)
{
    const int* cnt; int* off; int* psum; int n; int b;
    if ((int)blockIdx.x < nbE) { cnt = cntE; off = offE; psum = psumE; n = nE; b = blockIdx.x; }
    else { cnt = cntN; off = offN; psum = psumN; n = nN; b = blockIdx.x - nbE; }

    __shared__ int tsum[256];
    int base = b * 1024;
    int t = threadIdx.x;
    int idx0 = base + t * 4;
    int4 c = make_int4(0, 0, 0, 0);
    if (idx0 + 3 < n) c = *(const int4*)(cnt + idx0);
    else {
        if (idx0 + 0 < n) c.x = cnt[idx0 + 0];
        if (idx0 + 1 < n) c.y = cnt[idx0 + 1];
        if (idx0 + 2 < n) c.z = cnt[idx0 + 2];
        if (idx0 + 3 < n) c.w = cnt[idx0 + 3];
    }
    int s = c.x + c.y + c.z + c.w;
    tsum[t] = s;
    __syncthreads();
    for (int o = 1; o < 256; o <<= 1) {
        int v = (t >= o) ? tsum[t - o] : 0;
        __syncthreads();
        tsum[t] += v;
        __syncthreads();
    }
    int run = tsum[t] - s;
    run += c.x; if (idx0 + 0 < n) off[idx0 + 1] = run;
    run += c.y; if (idx0 + 1 < n) off[idx0 + 2] = run;
    run += c.z; if (idx0 + 2 < n) off[idx0 + 3] = run;
    run += c.w; if (idx0 + 3 < n) off[idx0 + 4] = run;
    if (t == 255) psum[b] = tsum[255];
}

__global__ __launch_bounds__(256) void scan_part2_dual(
    int* __restrict__ offE, const int* __restrict__ psumE, int nE, int nbE,
    int* __restrict__ offN, const int* __restrict__ psumN, int nN)
{
    int* off; const int* psum; int n; int b;
    if ((int)blockIdx.x < nbE) { off = offE; psum = psumE; n = nE; b = blockIdx.x; }
    else { off = offN; psum = psumN; n = nN; b = blockIdx.x - nbE; }

    __shared__ int bpref;
    int t = threadIdx.x;
    if (t < 64) {
        int s = (t < b) ? psum[t] : 0;
#pragma unroll
        for (int o = 32; o; o >>= 1) s += __shfl_xor(s, o);
        if (t == 0) {
            bpref = s;
            if (b == 0) off[0] = 0;
        }
    }
    __syncthreads();
    int base = b * 1024 + t * 4;
#pragma unroll
    for (int q = 0; q < 4; ++q) {
        int i = base + q;
        if (i < n) off[i + 1] += bpref;
    }
}

// =============== atomic-free CSR fill (rank-based) ===============
__global__ void fill_ranked_kernel(const int* __restrict__ V, const int* __restrict__ E,
                                   const int* __restrict__ rankE, const int* __restrict__ rankN,
                                   const int* __restrict__ eoff, const int* __restrict__ noff,
                                   int* __restrict__ edge_v, int* __restrict__ node_e, int nnz)
{
    int k0 = (blockIdx.x * blockDim.x + threadIdx.x) * 4;
    if (k0 >= nnz) return;
    int kmax = min(nnz - k0, 4);
    if (kmax == 4) {
        int4 v4 = *(const int4*)(V + k0);
        int4 e4 = *(const int4*)(E + k0);
        int4 re = *(const int4*)(rankE + k0);
        int4 rn = *(const int4*)(rankN + k0);
        edge_v[eoff[e4.x] + re.x] = v4.x;
        edge_v[eoff[e4.y] + re.y] = v4.y;
        edge_v[eoff[e4.z] + re.z] = v4.z;
        edge_v[eoff[e4.w] + re.w] = v4.w;
        node_e[noff[v4.x] + rn.x] = e4.x;
        node_e[noff[v4.y] + rn.y] = e4.y;
        node_e[noff[v4.z] + rn.z] = e4.z;
        node_e[noff[v4.w] + rn.w] = e4.w;
    } else {
        for (int q = 0; q < kmax; ++q) {
            int v = V[k0 + q], e = E[k0 + q];
            edge_v[eoff[e] + rankE[k0 + q]] = v;
            node_e[noff[v] + rankN[k0 + q]] = e;
        }
    }
}

// =============== graph kernels ===============
__device__ __forceinline__ float lrelu(float s) { return s >= 0.f ? s : 0.2f * s; }
// un-shifted softmax weight (R12); clamp 60 guards overflow; weights <= e^60,
// degree ~20 -> unnormalized acc <= ~1e27 << f32 max. divide-at-end.
__device__ __forceinline__ float ews(float s) { return expf(fminf(lrelu(s), 60.f)); }

// R13: SINGLE-PASS v2e — accumulate unnormalized weighted features and the
// weight sum together; normalize at the end. Removes the separate sum pass
// over edge_v+score. Every lane iterates all j, so every lane's wsum is the
// full segment sum (no shuffle needed).
__global__ void v2e_fused_kernel(const u16* __restrict__ Xf,
                                 const float* __restrict__ score,
                                 const int* __restrict__ eoff,
                                 const int* __restrict__ edge_v,
                                 u16* __restrict__ Ae, int M)
{
    int e = blockIdx.x * 8 + (threadIdx.x >> 5);
    if (e >= M) return;
    int sl = threadIdx.x & 31;
    int j0 = eoff[e], j1 = eoff[e + 1];

    float acc[8] = {0.f, 0.f, 0.f, 0.f, 0.f, 0.f, 0.f, 0.f};
    float wsum = 0.f;
    int col = sl * 8;
    int j = j0;
    for (; j + 3 < j1; j += 4) {
        int v0 = edge_v[j + 0], v1 = edge_v[j + 1], v2 = edge_v[j + 2], v3 = edge_v[j + 3];
        float s0 = score[v0], s1 = score[v1], s2 = score[v2], s3 = score[v3];
        u16x8 r0 = *(const u16x8*)(Xf + (size_t)v0 * 256 + col);
        u16x8 r1 = *(const u16x8*)(Xf + (size_t)v1 * 256 + col);
        u16x8 r2 = *(const u16x8*)(Xf + (size_t)v2 * 256 + col);
        u16x8 r3 = *(const u16x8*)(Xf + (size_t)v3 * 256 + col);
        float w0 = ews(s0);
        float w1 = ews(s1);
        float w2 = ews(s2);
        float w3 = ews(s3);
        wsum += w0 + w1 + w2 + w3;
#pragma unroll
        for (int q = 0; q < 8; ++q) {
            acc[q] += h2f(r0[q]) * w0;
            acc[q] += h2f(r1[q]) * w1;
            acc[q] += h2f(r2[q]) * w2;
            acc[q] += h2f(r3[q]) * w3;
        }
    }
    for (; j < j1; ++j) {
        int v = edge_v[j];
        float ww = ews(score[v]);
        wsum += ww;
        u16x8 r = *(const u16x8*)(Xf + (size_t)v * 256 + col);
#pragma unroll
        for (int q = 0; q < 8; ++q) acc[q] += h2f(r[q]) * ww;
    }
    float inv = (j1 > j0) ? 1.0f / wsum : 0.f;
    u16x8 hv;
#pragma unroll
    for (int q = 0; q < 8; ++q) {
        float vq = acc[q] * inv;
        vq = vq > 0.f ? vq : expm1f(vq);
        hv[q] = f2h(vq);
    }
    *(u16x8*)(Ae + (size_t)e * 320 + col) = hv;
}

// e2v + optional zero-tail; R13: 8-wide unroll (mean degree = NNZ/N = 8;
// doubles outstanding row loads in this L2-latency-bound loop)
__global__ void e2v_finish_kernel(const u16* __restrict__ Y,
                                  const int* __restrict__ noff,
                                  const int* __restrict__ node_e,
                                  const u16* __restrict__ Xinit,
                                  u16* __restrict__ H, int N,
                                  float* __restrict__ zbuf, int zN, int zTail)
{
    if ((int)blockIdx.x < zTail) {
        int id = (int)blockIdx.x * 256 + (int)threadIdx.x;
        if (id < zN) zbuf[id] = 0.f;
        return;
    }
    int v = ((int)blockIdx.x - zTail) * 8 + (threadIdx.x >> 5);
    if (v >= N) return;
    int sl = threadIdx.x & 31;
    int col = sl * 8;
    int i0 = noff[v], i1 = noff[v + 1];
    float acc[8] = {0.f, 0.f, 0.f, 0.f, 0.f, 0.f, 0.f, 0.f};
    int i = i0;
    for (; i + 7 < i1; i += 8) {
        int ee[8];
#pragma unroll
        for (int t = 0; t < 8; ++t) ee[t] = node_e[i + t];
        u16x8 rr[8];
#pragma unroll
        for (int t = 0; t < 8; ++t) rr[t] = *(const u16x8*)(Y + (size_t)ee[t] * 256 + col);
#pragma unroll
        for (int t = 0; t < 8; ++t)
#pragma unroll
            for (int q = 0; q < 8; ++q) acc[q] += h2f(rr[t][q]);
    }
    for (; i < i1; ++i) {
        int e = node_e[i];
        u16x8 r = *(const u16x8*)(Y + (size_t)e * 256 + col);
#pragma unroll
        for (int q = 0; q < 8; ++q) acc[q] += h2f(r[q]);
    }
    float inv = (i1 > i0) ? 1.0f / (float)(i1 - i0) : 0.f;
    size_t base = (size_t)v * 256 + col;
    u16x8 xi = *(const u16x8*)(Xinit + base);
    u16x8 hv;
#pragma unroll
    for (int q = 0; q < 8; ++q) {
        float mm = acc[q] * inv;
        float oq = (mm > 0.f ? mm : expm1f(mm)) + h2f(xi[q]);
        hv[q] = f2h(oq);
    }
    *(u16x8*)(H + base) = hv;
}

// =============== hyperconv ===============
__global__ void yh_kernel(const u16* __restrict__ Xc,
                          const int* __restrict__ eoff, const int* __restrict__ edge_v,
                          const int* __restrict__ noff, u16* __restrict__ Yh, int M)
{
    int e = blockIdx.x * 16 + (threadIdx.x >> 4);
    if (e >= M) return;
    int sl = threadIdx.x & 15;
    int col = sl * 8;
    int j0 = eoff[e], j1 = eoff[e + 1];

    float dsum = 0.f;
    for (int j = j0 + sl; j < j1; j += 16) {
        int v = edge_v[j];
        dsum += (float)(noff[v + 1] - noff[v]);
    }
#pragma unroll
    for (int o = 8; o; o >>= 1) dsum += __shfl_xor(dsum, o);
    float De = dsum / ((float)(j1 - j0) + 1.0f);
    float deinv = De > 0.f ? rsqrtf(De) : 1.0f;

    float acc[8] = {0.f, 0.f, 0.f, 0.f, 0.f, 0.f, 0.f, 0.f};
    int j = j0;
    for (; j + 3 < j1; j += 4) {
        int v0 = edge_v[j + 0], v1 = edge_v[j + 1], v2 = edge_v[j + 2], v3 = edge_v[j + 3];
        u16x8 r0 = *(const u16x8*)(Xc + (size_t)v0 * 128 + col);
        u16x8 r1 = *(const u16x8*)(Xc + (size_t)v1 * 128 + col);
        u16x8 r2 = *(const u16x8*)(Xc + (size_t)v2 * 128 + col);
        u16x8 r3 = *(const u16x8*)(Xc + (size_t)v3 * 128 + col);
#pragma unroll
        for (int q = 0; q < 8; ++q) {
            acc[q] += h2f(r0[q]);
            acc[q] += h2f(r1[q]);
            acc[q] += h2f(r2[q]);
            acc[q] += h2f(r3[q]);
        }
    }
    for (; j < j1; ++j) {
        int v = edge_v[j];
        u16x8 r = *(const u16x8*)(Xc + (size_t)v * 128 + col);
#pragma unroll
        for (int q = 0; q < 8; ++q) acc[q] += h2f(r[q]);
    }
    float sc = ((j1 > j0) ? 1.0f / (float)(j1 - j0) : 0.f) * deinv;
    u16x8 o8;
#pragma unroll
    for (int q = 0; q < 8; ++q) o8[q] = f2h(acc[q] * sc);
    *(u16x8*)(Yh + (size_t)e * 128 + col) = o8;
}

__global__ void xo_final_kernel(const u16* __restrict__ Yh,
                                const int* __restrict__ noff, const int* __restrict__ node_e,
                                float* __restrict__ out, int N)
{
    int v = blockIdx.x * 16 + (threadIdx.x >> 4);
    if (v >= N) return;
    int sl = threadIdx.x & 15;
    int col = sl * 8;
    int i0 = noff[v], i1 = noff[v + 1];
    float acc[8] = {0.f, 0.f, 0.f, 0.f, 0.f, 0.f, 0.f, 0.f};
    int i = i0;
    for (; i + 3 < i1; i += 4) {
        int e0 = node_e[i + 0], e1 = node_e[i + 1], e2 = node_e[i + 2], e3 = node_e[i + 3];
        u16x8 r0 = *(const u16x8*)(Yh + (size_t)e0 * 128 + col);
        u16x8 r1 = *(const u16x8*)(Yh + (size_t)e1 * 128 + col);
        u16x8 r2 = *(const u16x8*)(Yh + (size_t)e2 * 128 + col);
        u16x8 r3 = *(const u16x8*)(Yh + (size_t)e3 * 128 + col);
#pragma unroll
        for (int q = 0; q < 8; ++q) {
            acc[q] += h2f(r0[q]);
            acc[q] += h2f(r1[q]);
            acc[q] += h2f(r2[q]);
            acc[q] += h2f(r3[q]);
        }
    }
    for (; i < i1; ++i) {
        int e = node_e[i];
        u16x8 r = *(const u16x8*)(Yh + (size_t)e * 128 + col);
#pragma unroll
        for (int q = 0; q < 8; ++q) acc[q] += h2f(r[q]);
    }
    float sc = (i1 > i0) ? rsqrtf((float)(i1 - i0)) : 0.f;
    float4 oA, oB;
    oA.x = acc[0] * sc; oA.y = acc[1] * sc; oA.z = acc[2] * sc; oA.w = acc[3] * sc;
    oB.x = acc[4] * sc; oB.y = acc[5] * sc; oB.z = acc[6] * sc; oB.w = acc[7] * sc;
    float* d = out + (size_t)v * 128 + col;
    *(float4*)d = oA;
    *(float4*)(d + 4) = oB;
}

// =============== host-side ===============
static void gemm128(const u16* A, int lda,
                    const u16* B, int ldb,
                    const float* biasF, const float* biasB,
                    u16* CbA, u16* CbB,
                    const float* avec, float* scoreOut,
                    const int* cV, const int* cE, int* ecnt, int* ncnt,
                    int* rankE, int* rankN, int tNnz,
                    int M, int Nc, int ncSplit, int K,
                    hipStream_t stream)
{
    int nrb = (M + 127) / 128, ncb = Nc / 128;
    int nrb8 = ((nrb + 7) / 8) * 8;
    int nGemm = nrb8 * ncb;
    int nCnt = (cV != nullptr) ? (tNnz + 2047) / 2048 : 0;
    int T = nGemm + nCnt;
    int sStride = nCnt ? max(T / nCnt, 1) : 1;
    gemm_mfma128_kernel<<<T, 256, 0, stream>>>(
        A, lda, B, ldb, biasF, biasB, CbA, CbB, avec, scoreOut,
        cV, cE, ecnt, ncnt, rankE, rankN, tNnz, nCnt, sStride,
        M, Nc, ncSplit, K, nrb, ncb);
}

static void gemm64(const u16* A, int lda,
                   const u16* B, int ldb,
                   const float* biasF, const float* biasB,
                   u16* CbA, u16* CbB,
                   const float* avec, float* scoreOut,
                   int M, int Nc, int ncSplit, int K,
                   hipStream_t stream)
{
    int nrb = (M + 127) / 128, ncb = Nc / 64;
    int nrb8 = ((nrb + 7) / 8) * 8;
    gemm_mfma64_kernel<<<nrb8 * ncb, 256, 0, stream>>>(
        A, lda, B, ldb, biasF, biasB, CbA, CbB, avec, scoreOut,
        M, Nc, ncSplit, K, nrb, ncb);
}

extern "C" void kernel_launch(void* const* d_in, const int* in_sizes, int n_in,
                              void* d_out, int out_size, void* d_ws, size_t ws_size,
                              hipStream_t stream)
{
    const float* X   = (const float*)d_in[0];
    const int*   V   = (const int*)d_in[1];
    const int*   E   = (const int*)d_in[2];
    const float* S   = (const float*)d_in[3];
    const float* Wx0 = (const float*)d_in[4];  const float* bx0 = (const float*)d_in[5];
    const float* Wv0 = (const float*)d_in[6];  const float* bv0 = (const float*)d_in[7];
    const float* a0  = (const float*)d_in[8];
    const float* Wt0 = (const float*)d_in[9];  const float* bt0 = (const float*)d_in[10];
    const float* Wx1 = (const float*)d_in[11]; const float* bx1 = (const float*)d_in[12];
    const float* Wv1 = (const float*)d_in[13]; const float* bv1 = (const float*)d_in[14];
    const float* a1  = (const float*)d_in[15];
    const float* Wt1 = (const float*)d_in[16]; const float* bt1 = (const float*)d_in[17];
    const float* Wf  = (const float*)d_in[18]; const float* bf  = (const float*)d_in[19];

    int N   = in_sizes[0] / 128;
    int NNZ = in_sizes[1];
    int M   = in_sizes[3] / 64;

    float* ws = (float*)d_ws;
    size_t off = 0;
    u16* XinitB = (u16*)(ws + off); off += (size_t)N * 128;  // [N,256] f16; also Yh [M,128] f16
    u16* XfeatR = (u16*)(ws + off); off += (size_t)N * 128;  // Xfeatb/Ybufb/Xcb
    u16* Xfeatb = XfeatR;
    u16* Ybufb  = XfeatR;
    u16* Abuf = (u16*)(ws + off); off += (size_t)N * 128;    // [N,256] f16: X cast / h
    u16* Ae   = (u16*)(ws + off); off += (size_t)M * 160;    // [M,320] f16 edge buffer
    u16* WxvT0 = (u16*)(ws + off); off += (size_t)(512 * 128) / 2;
    u16* WtT0  = (u16*)(ws + off); off += (size_t)(256 * 320) / 2;
    u16* WxvT1 = (u16*)(ws + off); off += (size_t)(512 * 256) / 2;
    u16* WtT1  = (u16*)(ws + off); off += (size_t)(256 * 320) / 2;
    u16* WfT   = (u16*)(ws + off); off += (size_t)(128 * 256) / 2;
    // ecnt | ncnt | score contiguous -> one zero pass covers all three
    int* ecnt   = (int*)(ws + off); off += (size_t)M;
    int* ncnt   = (int*)(ws + off); off += (size_t)N;
    float* score = ws + off;        off += (size_t)N;
    int* eoff   = (int*)(ws + off); off += (size_t)(M + 1);
    int* psumE  = (int*)(ws + off); off += 64;
    int* edge_v = (int*)(ws + off); off += (size_t)NNZ;
    int* noff   = (int*)(ws + off); off += (size_t)(N + 1);
    int* psumN  = (int*)(ws + off); off += 64;
    int* node_e = (int*)(ws + off); off += (size_t)NNZ;
    int* rankE  = (int*)(ws + off); off += (size_t)NNZ;
    int* rankN  = (int*)(ws + off); off += (size_t)NNZ;

    // ---- fused prep: zero (ecnt|ncnt|score) + input casts + weight casts ----
    int n4x = N * 128 / 4, nS = M * 64;
    int zN4 = (M + 2 * N) / 4;                 // M, N multiples of 4 here
    int nbZero = (zN4 + 255) / 256;
    int nbCast = (n4x + nS + 255) / 256;
    WJobs jobs;
    jobs.j[0] = {Wx0, WxvT0,             128, 8};
    jobs.j[1] = {Wv0, WxvT0 + 256 * 128, 128, 8};
    jobs.j[2] = {Wt0, WtT0,              320, 8};
    jobs.j[3] = {Wx1, WxvT1,             256, 8};
    jobs.j[4] = {Wv1, WxvT1 + 256 * 256, 256, 8};
    jobs.j[5] = {Wt1, WtT1,              320, 8};
    jobs.j[6] = {Wf,  WfT,               256, 7};
    int nbW = 7 * 320;
    prep_fused_kernel<<<nbZero + nbCast + nbW, 256, 0, stream>>>(
        ecnt, zN4, nbZero, X, Abuf, n4x, S, Ae, nS, nbCast, jobs);

    // ---- layer 0 X-GEMM (128x128) carries dispersed count blocks ----
    gemm128(Abuf, 128, WxvT0, 128, bx0, bv0, XinitB, Xfeatb, a0, score,
            V, E, ecnt, ncnt, rankE, rankN, NNZ, N, 512, 256, 128, stream);

    // ---- scans (exclusive offsets from counts) ----
    int nbE = (M + 1023) / 1024, nbN = (N + 1023) / 1024;
    scan_part1_dual<<<nbE + nbN, 256, 0, stream>>>(ecnt, eoff, psumE, M, nbE,
                                                   ncnt, noff, psumN, N);
    scan_part2_dual<<<nbE + nbN, 256, 0, stream>>>(eoff, psumE, M, nbE,
                                                   noff, psumN, N);

    // ---- atomic-free CSR fill (both edge_v and node_e) ----
    fill_ranked_kernel<<<((NNZ + 3) / 4 + 255) / 256, 256, 0, stream>>>(
        V, E, rankE, rankN, eoff, noff, edge_v, node_e, NNZ);

    // ---- layer 0 rest ----
    v2e_fused_kernel<<<(M + 7) / 8, 256, 0, stream>>>(Xfeatb, score, eoff, edge_v, Ae, M);
    gemm64(Ae, 320, WtT0, 320, nullptr, bt0, nullptr, Ybufb, nullptr, nullptr,
           M, 256, 0, 320, stream);
    {   // e2v + zero score for layer 1
        int zTail = (N + 255) / 256;
        e2v_finish_kernel<<<zTail + (N + 7) / 8, 256, 0, stream>>>(
            Ybufb, noff, node_e, XinitB, Abuf, N, score, N, zTail);
    }

    // ---- layer 1 ----
    gemm128(Abuf, 256, WxvT1, 256, bx1, bv1, XinitB, Xfeatb, a1, score,
            nullptr, nullptr, nullptr, nullptr, nullptr, nullptr, 0,
            N, 512, 256, 256, stream);
    v2e_fused_kernel<<<(M + 7) / 8, 256, 0, stream>>>(Xfeatb, score, eoff, edge_v, Ae, M);
    gemm64(Ae, 320, WtT1, 320, nullptr, bt1, nullptr, Ybufb, nullptr, nullptr,
           M, 256, 0, 320, stream);
    e2v_finish_kernel<<<(N + 7) / 8, 256, 0, stream>>>(
        Ybufb, noff, node_e, XinitB, Abuf, N, nullptr, 0, 0);

    // ---- hyperconv (all-f16 intermediates, fp32 final out) ----
    u16* Xcb = XfeatR;   // [N,128] f16
    u16* Yhb = XinitB;   // [M,128] f16
    gemm64(Abuf, 256, WfT, 256, bf, nullptr, Xcb, nullptr, nullptr, nullptr,
           N, 128, 128, 256, stream);
    yh_kernel<<<(M + 15) / 16, 256, 0, stream>>>(Xcb, eoff, edge_v, noff, Yhb, M);
    xo_final_kernel<<<(N + 15) / 16, 256, 0, stream>>>(Yhb, noff, node_e, (float*)d_out, N);
}

// Round 14
// 433.453 us; speedup vs baseline: 1.0445x; 1.0445x over previous
//
#include <hip/hip_runtime.h>

typedef unsigned short u16;
typedef __attribute__((ext_vector_type(4))) u16 u16x4;
typedef __attribute__((ext_vector_type(8))) u16 u16x8;
typedef __attribute__((ext_vector_type(8))) _Float16 f16x8;
typedef __attribute__((ext_vector_type(4))) float f32x4;

__device__ __forceinline__ u16 f2h(float x) {
    _Float16 h = (_Float16)x;
    return __builtin_bit_cast(u16, h);
}
__device__ __forceinline__ float h2f(u16 u) {
    return (float)__builtin_bit_cast(_Float16, u);
}

__device__ __forceinline__ void gl_lds16(const void* g, void* l) {
    __builtin_amdgcn_global_load_lds(
        (const __attribute__((address_space(1))) void*)g,
        (__attribute__((address_space(3))) void*)l, 16, 0, 0);
}

// ===== fp16 GEMM, 128x128 tile + dispersed count (R12 verbatim) =====
__global__ __launch_bounds__(256) void gemm_mfma128_kernel(
    const u16* __restrict__ A, int lda,
    const u16* __restrict__ B, int ldb,
    const float* __restrict__ biasF, const float* __restrict__ biasB,
    u16* __restrict__ CbA, u16* __restrict__ CbB,
    const float* __restrict__ avec, float* __restrict__ scoreOut,
    const int* __restrict__ cV, const int* __restrict__ cE,
    int* __restrict__ ecnt, int* __restrict__ ncnt,
    int* __restrict__ rankE, int* __restrict__ rankN, int tNnz,
    int nCnt, int sStride,
    int M, int Nc, int ncSplit, int K, int nrb, int ncb)
{
    int g0 = blockIdx.x;
    int g = g0;
    if (nCnt > 0) {
        int nc1 = (g0 + 1) / sStride;
        int cIdx = nc1 - 1;
        if (((g0 + 1) % sStride == 0) && cIdx < nCnt) {
            // ---- dedicated count block (8 entries/thread) ----
            int k0 = (cIdx * 256 + (int)threadIdx.x) * 8;
            if (k0 >= tNnz) return;
            int kmax = min(tNnz - k0, 8);
            int vv[8], ee[8], rE[8], rN[8];
            if (kmax == 8) {
                int4 a = *(const int4*)(cV + k0), b = *(const int4*)(cV + k0 + 4);
                int4 c = *(const int4*)(cE + k0), d = *(const int4*)(cE + k0 + 4);
                vv[0]=a.x; vv[1]=a.y; vv[2]=a.z; vv[3]=a.w; vv[4]=b.x; vv[5]=b.y; vv[6]=b.z; vv[7]=b.w;
                ee[0]=c.x; ee[1]=c.y; ee[2]=c.z; ee[3]=c.w; ee[4]=d.x; ee[5]=d.y; ee[6]=d.z; ee[7]=d.w;
            } else {
                for (int q = 0; q < kmax; ++q) { vv[q] = cV[k0 + q]; ee[q] = cE[k0 + q]; }
            }
            for (int q = 0; q < kmax; ++q) rE[q] = atomicAdd(&ecnt[ee[q]], 1);
            for (int q = 0; q < kmax; ++q) rN[q] = atomicAdd(&ncnt[vv[q]], 1);
            if (kmax == 8) {
                int4 r0, r1;
                r0.x=rE[0]; r0.y=rE[1]; r0.z=rE[2]; r0.w=rE[3];
                r1.x=rE[4]; r1.y=rE[5]; r1.z=rE[6]; r1.w=rE[7];
                *(int4*)(rankE + k0) = r0;
                *(int4*)(rankE + k0 + 4) = r1;
                r0.x=rN[0]; r0.y=rN[1]; r0.z=rN[2]; r0.w=rN[3];
                r1.x=rN[4]; r1.y=rN[5]; r1.z=rN[6]; r1.w=rN[7];
                *(int4*)(rankN + k0) = r0;
                *(int4*)(rankN + k0 + 4) = r1;
            } else {
                for (int q = 0; q < kmax; ++q) { rankE[k0 + q] = rE[q]; rankN[k0 + q] = rN[q]; }
            }
            return;
        }
        g = g0 - min(nc1, nCnt);
    }

    int xcd = g & 7;
    int slot = g >> 3;
    int rbi = slot / ncb;
    int cb = slot - rbi * ncb;
    int rb = xcd + 8 * rbi;
    if (rb >= nrb) return;

    __shared__ __align__(16) u16 lds[16384];   // 32 KB: A 2x8192B, B 2x8192B
    u16* sA0 = lds;
    u16* sA1 = lds + 4096;
    u16* sB0 = lds + 8192;
    u16* sB1 = lds + 12288;

    int tid = threadIdx.x;
    int wave = tid >> 6, lane = tid & 63;
    int row0 = rb * 128, col0 = cb * 128;

    long gA[2], gB[2];
    int sOff[2];
#pragma unroll
    for (int r = 0; r < 2; ++r) {
        int trow = r * 64 + wave * 16 + (lane >> 2);
        int chunk = (lane & 3) ^ ((trow >> 2) & 3);
        int arow = min(row0 + trow, M - 1);
        gA[r] = (long)arow * lda + chunk * 8;
        gB[r] = (long)(col0 + trow) * ldb + chunk * 8;
        sOff[r] = (r * 64 + wave * 16) * 32;
    }

    int m16 = lane & 15, quad = lane >> 4;
    int offA[4], offB[4];
#pragma unroll
    for (int i = 0; i < 4; ++i) {
        int ra = (wave & 1) * 64 + i * 16 + m16;
        offA[i] = ra * 32 + ((quad ^ ((ra >> 2) & 3)) * 8);
    }
#pragma unroll
    for (int j = 0; j < 4; ++j) {
        int rbx = (wave >> 1) * 64 + j * 16 + m16;
        offB[j] = rbx * 32 + ((quad ^ ((rbx >> 2) & 3)) * 8);
    }

    f32x4 acc[4][4];
#pragma unroll
    for (int i = 0; i < 4; ++i)
#pragma unroll
        for (int j = 0; j < 4; ++j) {
            f32x4 z = {0.f, 0.f, 0.f, 0.f};
            acc[i][j] = z;
        }

    int nkb = K >> 6;   // BK = 64
    for (int kb = 0; kb < nkb; ++kb) {
#pragma unroll
        for (int r = 0; r < 2; ++r) {
            gl_lds16(A + gA[r], sA0 + sOff[r]);
            gl_lds16(A + gA[r] + 32, sA1 + sOff[r]);
            gl_lds16(B + gB[r], sB0 + sOff[r]);
            gl_lds16(B + gB[r] + 32, sB1 + sOff[r]);
        }
        __syncthreads();
        {
            f16x8 av[4], bv[4];
#pragma unroll
            for (int i = 0; i < 4; ++i) av[i] = *(const f16x8*)(sA0 + offA[i]);
#pragma unroll
            for (int j = 0; j < 4; ++j) bv[j] = *(const f16x8*)(sB0 + offB[j]);
#pragma unroll
            for (int i = 0; i < 4; ++i)
#pragma unroll
                for (int j = 0; j < 4; ++j)
                    acc[i][j] = __builtin_amdgcn_mfma_f32_16x16x32_f16(av[i], bv[j], acc[i][j], 0, 0, 0);
        }
        {
            f16x8 av[4], bv[4];
#pragma unroll
            for (int i = 0; i < 4; ++i) av[i] = *(const f16x8*)(sA1 + offA[i]);
#pragma unroll
            for (int j = 0; j < 4; ++j) bv[j] = *(const f16x8*)(sB1 + offB[j]);
#pragma unroll
            for (int i = 0; i < 4; ++i)
#pragma unroll
                for (int j = 0; j < 4; ++j)
                    acc[i][j] = __builtin_amdgcn_mfma_f32_16x16x32_f16(av[i], bv[j], acc[i][j], 0, 0, 0);
        }
        __syncthreads();
#pragma unroll
        for (int r = 0; r < 2; ++r) { gA[r] += 64; gB[r] += 64; }
    }

    // ---- epilogue: two 64x32 LDS-transpose passes staged in regs, then one
    //      contiguous 128B store burst per row ----
    int rbase = (wave & 1) * 64, cbase = (wave >> 1) * 64;
    float bj[4];
#pragma unroll
    for (int j = 0; j < 4; ++j) {
        int col = col0 + cbase + j * 16 + m16;
        bj[j] = (col >= ncSplit) ? biasB[col - ncSplit] : biasF[col];
    }
    bool isB = (col0 >= ncSplit);            // 128-aligned splits: tile-uniform
    u16* Cp = isB ? CbB : CbA;
    int stride = isB ? (Nc - ncSplit) : ncSplit;
    int ccb = (col0 + cbase) - (isB ? ncSplit : 0);
    bool doScore = (scoreOut != nullptr) && isB;
    int row = row0 + rbase + lane;
    u16* wlds = lds + wave * 2560;           // 64 rows x 40 u16 per wave
    u16x8 creg[2][4];
#pragma unroll
    for (int h = 0; h < 2; ++h) {
        __syncthreads();
#pragma unroll
        for (int jj = 0; jj < 2; ++jj) {
            int j = h * 2 + jj;
#pragma unroll
            for (int i = 0; i < 4; ++i)
#pragma unroll
                for (int rr = 0; rr < 4; ++rr) {
                    int lr = i * 16 + quad * 4 + rr;
                    int lc = jj * 16 + m16;
                    int seg = (lc >> 3) ^ ((lr >> 2) & 3);
                    wlds[lr * 40 + seg * 8 + (lc & 7)] = f2h(acc[i][j][rr] + bj[j]);
                }
        }
        __syncthreads();
#pragma unroll
        for (int s = 0; s < 4; ++s) {
            int sseg = s ^ ((lane >> 2) & 3);
            creg[h][s] = *(const u16x8*)(wlds + lane * 40 + sseg * 8);
        }
    }
    if (row < M) {
        u16* dst = Cp + (size_t)row * stride + ccb;
        float sp = 0.f;
#pragma unroll
        for (int h = 0; h < 2; ++h)
#pragma unroll
            for (int s = 0; s < 4; ++s) {
                *(u16x8*)(dst + h * 32 + s * 8) = creg[h][s];
                if (doScore) {
#pragma unroll
                    for (int q = 0; q < 8; ++q)
                        sp += h2f(creg[h][s][q]) * avec[ccb + h * 32 + s * 8 + q];
                }
            }
        if (doScore) atomicAdd(scoreOut + row, sp);
    }
}

// ===== fp16 GEMM, 128x64 tile (R6 verbatim) =====
__global__ __launch_bounds__(256) void gemm_mfma64_kernel(
    const u16* __restrict__ A, int lda,
    const u16* __restrict__ B, int ldb,
    const float* __restrict__ biasF, const float* __restrict__ biasB,
    u16* __restrict__ CbA, u16* __restrict__ CbB,
    const float* __restrict__ avec, float* __restrict__ scoreOut,
    int M, int Nc, int ncSplit, int K, int nrb, int ncb)
{
    int g = blockIdx.x;
    int xcd = g & 7;
    int slot = g >> 3;
    int rbi = slot / ncb;
    int cb = slot - rbi * ncb;
    int rb = xcd + 8 * rbi;
    if (rb >= nrb) return;

    __shared__ __align__(16) u16 lds[12288];   // 24 KB: A 2x4096, B 2x2048
    u16* sA0 = lds;
    u16* sA1 = lds + 4096;
    u16* sB0 = lds + 8192;
    u16* sB1 = lds + 10240;

    int tid = threadIdx.x;
    int wave = tid >> 6, lane = tid & 63;
    int row0 = rb * 128, col0 = cb * 64;

    long gA[2];
    int sOffA[2];
#pragma unroll
    for (int r = 0; r < 2; ++r) {
        int trow = r * 64 + wave * 16 + (lane >> 2);
        int chunk = (lane & 3) ^ ((trow >> 2) & 3);
        int arow = min(row0 + trow, M - 1);
        gA[r] = (long)arow * lda + chunk * 8;
        sOffA[r] = (r * 64 + wave * 16) * 32;
    }
    int trowB = wave * 16 + (lane >> 2);
    int chunkB = (lane & 3) ^ ((trowB >> 2) & 3);
    long gB = (long)(col0 + trowB) * ldb + chunkB * 8;
    int sOffB = (wave * 16) * 32;

    int m16 = lane & 15, quad = lane >> 4;
    int offA[4], offB[2];
#pragma unroll
    for (int i = 0; i < 4; ++i) {
        int ra = (wave & 1) * 64 + i * 16 + m16;
        offA[i] = ra * 32 + ((quad ^ ((ra >> 2) & 3)) * 8);
    }
#pragma unroll
    for (int j = 0; j < 2; ++j) {
        int rbx = (wave >> 1) * 32 + j * 16 + m16;
        offB[j] = rbx * 32 + ((quad ^ ((rbx >> 2) & 3)) * 8);
    }

    f32x4 acc[4][2];
#pragma unroll
    for (int i = 0; i < 4; ++i)
#pragma unroll
        for (int j = 0; j < 2; ++j) {
            f32x4 z = {0.f, 0.f, 0.f, 0.f};
            acc[i][j] = z;
        }

    int nkb = K >> 6;   // BK = 64
    for (int kb = 0; kb < nkb; ++kb) {
#pragma unroll
        for (int r = 0; r < 2; ++r) {
            gl_lds16(A + gA[r], sA0 + sOffA[r]);
            gl_lds16(A + gA[r] + 32, sA1 + sOffA[r]);
        }
        gl_lds16(B + gB, sB0 + sOffB);
        gl_lds16(B + gB + 32, sB1 + sOffB);
        __syncthreads();
        {
            f16x8 av[4], bv[2];
#pragma unroll
            for (int i = 0; i < 4; ++i) av[i] = *(const f16x8*)(sA0 + offA[i]);
#pragma unroll
            for (int j = 0; j < 2; ++j) bv[j] = *(const f16x8*)(sB0 + offB[j]);
#pragma unroll
            for (int i = 0; i < 4; ++i)
#pragma unroll
                for (int j = 0; j < 2; ++j)
                    acc[i][j] = __builtin_amdgcn_mfma_f32_16x16x32_f16(av[i], bv[j], acc[i][j], 0, 0, 0);
        }
        {
            f16x8 av[4], bv[2];
#pragma unroll
            for (int i = 0; i < 4; ++i) av[i] = *(const f16x8*)(sA1 + offA[i]);
#pragma unroll
            for (int j = 0; j < 2; ++j) bv[j] = *(const f16x8*)(sB1 + offB[j]);
#pragma unroll
            for (int i = 0; i < 4; ++i)
#pragma unroll
                for (int j = 0; j < 2; ++j)
                    acc[i][j] = __builtin_amdgcn_mfma_f32_16x16x32_f16(av[i], bv[j], acc[i][j], 0, 0, 0);
        }
        __syncthreads();
#pragma unroll
        for (int r = 0; r < 2; ++r) gA[r] += 64;
        gB += 64;
    }

    // ---- epilogue: per-wave LDS transpose (64 rows x 32 cols), 16B stores ----
    int rbase = (wave & 1) * 64, cbase = (wave >> 1) * 32;
    float bj[2];
#pragma unroll
    for (int j = 0; j < 2; ++j) {
        int col = col0 + cbase + j * 16 + m16;
        bj[j] = (col >= ncSplit) ? biasB[col - ncSplit] : biasF[col];
    }
    u16* wlds = lds + wave * 2560;   // 64 rows x 40 u16
    __syncthreads();
#pragma unroll
    for (int j = 0; j < 2; ++j)
#pragma unroll
        for (int i = 0; i < 4; ++i)
#pragma unroll
            for (int rr = 0; rr < 4; ++rr) {
                int lr = i * 16 + quad * 4 + rr;
                int lc = j * 16 + m16;
                int seg = (lc >> 3) ^ ((lr >> 2) & 3);
                wlds[lr * 40 + seg * 8 + (lc & 7)] = f2h(acc[i][j][rr] + bj[j]);
            }
    __syncthreads();
    {
        int colbase = col0 + cbase;
        bool isB = (colbase >= ncSplit);
        u16* Cp = isB ? CbB : CbA;
        int stride = isB ? (Nc - ncSplit) : ncSplit;
        int cc = isB ? (colbase - ncSplit) : colbase;
        bool doScore = (scoreOut != nullptr) && isB;
        int row = row0 + rbase + lane;
        if (row < M) {
            float sp = 0.f;
#pragma unroll
            for (int s = 0; s < 4; ++s) {
                int sseg = s ^ ((lane >> 2) & 3);
                u16x8 vv = *(const u16x8*)(wlds + lane * 40 + sseg * 8);
                *(u16x8*)(Cp + (size_t)row * stride + cc + s * 8) = vv;
                if (doScore) {
#pragma unroll
                    for (int q = 0; q < 8; ++q)
                        sp += h2f(vv[q]) * avec[cc + s * 8 + q];
                }
            }
            if (doScore) atomicAdd(scoreOut + row, sp);
        }
    }
}

// ====== fused prep: zero-tail + input casts + weight casts (no atomics) ======
struct WJob { const float* W; u16* Wt; int K; int ncShift; };
struct WJobs { WJob j[7]; };

__global__ void prep_fused_kernel(
    int* __restrict__ zbuf, int zN4, int nbZero,      // zero zN4 int4's
    const float* __restrict__ X, u16* __restrict__ Abuf, int n4x,
    const float* __restrict__ S, u16* __restrict__ Ae, int nS, int nbCast,
    WJobs jobs)
{
    int b = blockIdx.x;
    if (b < nbZero) {
        int id = b * 256 + (int)threadIdx.x;
        if (id < zN4) ((int4*)zbuf)[id] = make_int4(0, 0, 0, 0);
        return;
    }
    if (b < nbZero + nbCast) {
        int id = (b - nbZero) * 256 + (int)threadIdx.x;
        if (id < n4x) {
            float4 x = ((const float4*)X)[id];
            u16x4 h;
            h.x = f2h(x.x); h.y = f2h(x.y); h.z = f2h(x.z); h.w = f2h(x.w);
            *(u16x4*)(Abuf + (size_t)id * 4) = h;
        } else {
            int i = id - n4x;
            if (i < nS) {
                int e = i >> 6, c = i & 63;
                Ae[(size_t)e * 320 + 256 + c] = f2h(S[i]);
            }
        }
        return;
    }
    int bb = b - nbZero - nbCast;
    int job = bb / 320, rem = bb - job * 320;
    WJob jb = jobs.j[job];
    int Nc = 1 << jb.ncShift;
    int idx = rem * 256 + (int)threadIdx.x;
    if (idx >= jb.K * Nc) return;
    int k = idx >> jb.ncShift, n = idx & (Nc - 1);
    jb.Wt[(size_t)n * jb.K + k] = f2h(jb.W[idx]);
}

// =============== dual-array scans ===============
__global__ __launch_bounds__(256) void scan_part1_dual(
    const int* __restrict__ cntE, int* __restrict__ offE, int* __restrict__ psumE, int nE, int nbE,
    const int* __restrict__ cntN, int* __restrict__ offN, int* __restrict__ psumN, int nN)
{
    const int* cnt; int* off; int* psum; int n; int b;
    if ((int)blockIdx.x < nbE) { cnt = cntE; off = offE; psum = psumE; n = nE; b = blockIdx.x; }
    else { cnt = cntN; off = offN; psum = psumN; n = nN; b = blockIdx.x - nbE; }

    __shared__ int tsum[256];
    int base = b * 1024;
    int t = threadIdx.x;
    int idx0 = base + t * 4;
    int4 c = make_int4(0, 0, 0, 0);
    if (idx0 + 3 < n) c = *(const int4*)(cnt + idx0);
    else {
        if (idx0 + 0 < n) c.x = cnt[idx0 + 0];
        if (idx0 + 1 < n) c.y = cnt[idx0 + 1];
        if (idx0 + 2 < n) c.z = cnt[idx0 + 2];
        if (idx0 + 3 < n) c.w = cnt[idx0 + 3];
    }
    int s = c.x + c.y + c.z + c.w;
    tsum[t] = s;
    __syncthreads();
    for (int o = 1; o < 256; o <<= 1) {
        int v = (t >= o) ? tsum[t - o] : 0;
        __syncthreads();
        tsum[t] += v;
        __syncthreads();
    }
    int run = tsum[t] - s;
    run += c.x; if (idx0 + 0 < n) off[idx0 + 1] = run;
    run += c.y; if (idx0 + 1 < n) off[idx0 + 2] = run;
    run += c.z; if (idx0 + 2 < n) off[idx0 + 3] = run;
    run += c.w; if (idx0 + 3 < n) off[idx0 + 4] = run;
    if (t == 255) psum[b] = tsum[255];
}

__global__ __launch_bounds__(256) void scan_part2_dual(
    int* __restrict__ offE, const int* __restrict__ psumE, int nE, int nbE,
    int* __restrict__ offN, const int* __restrict__ psumN, int nN)
{
    int* off; const int* psum; int n; int b;
    if ((int)blockIdx.x < nbE) { off = offE; psum = psumE; n = nE; b = blockIdx.x; }
    else { off = offN; psum = psumN; n = nN; b = blockIdx.x - nbE; }

    __shared__ int bpref;
    int t = threadIdx.x;
    if (t < 64) {
        int s = (t < b) ? psum[t] : 0;
#pragma unroll
        for (int o = 32; o; o >>= 1) s += __shfl_xor(s, o);
        if (t == 0) {
            bpref = s;
            if (b == 0) off[0] = 0;
        }
    }
    __syncthreads();
    int base = b * 1024 + t * 4;
#pragma unroll
    for (int q = 0; q < 4; ++q) {
        int i = base + q;
        if (i < n) off[i + 1] += bpref;
    }
}

// =============== atomic-free CSR fill (rank-based) ===============
__global__ void fill_ranked_kernel(const int* __restrict__ V, const int* __restrict__ E,
                                   const int* __restrict__ rankE, const int* __restrict__ rankN,
                                   const int* __restrict__ eoff, const int* __restrict__ noff,
                                   int* __restrict__ edge_v, int* __restrict__ node_e, int nnz)
{
    int k0 = (blockIdx.x * blockDim.x + threadIdx.x) * 4;
    if (k0 >= nnz) return;
    int kmax = min(nnz - k0, 4);
    if (kmax == 4) {
        int4 v4 = *(const int4*)(V + k0);
        int4 e4 = *(const int4*)(E + k0);
        int4 re = *(const int4*)(rankE + k0);
        int4 rn = *(const int4*)(rankN + k0);
        edge_v[eoff[e4.x] + re.x] = v4.x;
        edge_v[eoff[e4.y] + re.y] = v4.y;
        edge_v[eoff[e4.z] + re.z] = v4.z;
        edge_v[eoff[e4.w] + re.w] = v4.w;
        node_e[noff[v4.x] + rn.x] = e4.x;
        node_e[noff[v4.y] + rn.y] = e4.y;
        node_e[noff[v4.z] + rn.z] = e4.z;
        node_e[noff[v4.w] + rn.w] = e4.w;
    } else {
        for (int q = 0; q < kmax; ++q) {
            int v = V[k0 + q], e = E[k0 + q];
            edge_v[eoff[e] + rankE[k0 + q]] = v;
            node_e[noff[v] + rankN[k0 + q]] = e;
        }
    }
}

// =============== graph kernels ===============
__device__ __forceinline__ float lrelu(float s) { return s >= 0.f ? s : 0.2f * s; }
// un-shifted softmax weight; clamp 60 guards overflow.
__device__ __forceinline__ float ews(float s) { return expf(fminf(lrelu(s), 60.f)); }

__global__ void v2e_fused_kernel(const u16* __restrict__ Xf,
                                 const float* __restrict__ score,
                                 const int* __restrict__ eoff,
                                 const int* __restrict__ edge_v,
                                 u16* __restrict__ Ae, int M)
{
    int e = blockIdx.x * 8 + (threadIdx.x >> 5);
    if (e >= M) return;
    int sl = threadIdx.x & 31;
    int j0 = eoff[e], j1 = eoff[e + 1];
    float sum = 0.f;
    for (int j = j0 + sl; j < j1; j += 32) sum += ews(score[edge_v[j]]);
#pragma unroll
    for (int o = 16; o; o >>= 1) sum += __shfl_xor(sum, o);
    float inv = (j1 > j0) ? 1.0f / sum : 0.f;

    float acc[8] = {0.f, 0.f, 0.f, 0.f, 0.f, 0.f, 0.f, 0.f};
    int col = sl * 8;
    int j = j0;
    for (; j + 3 < j1; j += 4) {
        int v0 = edge_v[j + 0], v1 = edge_v[j + 1], v2 = edge_v[j + 2], v3 = edge_v[j + 3];
        float s0 = score[v0], s1 = score[v1], s2 = score[v2], s3 = score[v3];
        u16x8 r0 = *(const u16x8*)(Xf + (size_t)v0 * 256 + col);
        u16x8 r1 = *(const u16x8*)(Xf + (size_t)v1 * 256 + col);
        u16x8 r2 = *(const u16x8*)(Xf + (size_t)v2 * 256 + col);
        u16x8 r3 = *(const u16x8*)(Xf + (size_t)v3 * 256 + col);
        float w0 = ews(s0) * inv;
        float w1 = ews(s1) * inv;
        float w2 = ews(s2) * inv;
        float w3 = ews(s3) * inv;
#pragma unroll
        for (int q = 0; q < 8; ++q) {
            acc[q] += h2f(r0[q]) * w0;
            acc[q] += h2f(r1[q]) * w1;
            acc[q] += h2f(r2[q]) * w2;
            acc[q] += h2f(r3[q]) * w3;
        }
    }
    for (; j < j1; ++j) {
        int v = edge_v[j];
        float ww = ews(score[v]) * inv;
        u16x8 r = *(const u16x8*)(Xf + (size_t)v * 256 + col);
#pragma unroll
        for (int q = 0; q < 8; ++q) acc[q] += h2f(r[q]) * ww;
    }
    u16x8 hv;
#pragma unroll
    for (int q = 0; q < 8; ++q) {
        float vq = acc[q];
        vq = vq > 0.f ? vq : expm1f(vq);
        hv[q] = f2h(vq);
    }
    *(u16x8*)(Ae + (size_t)e * 320 + col) = hv;
}

// e2v + optional zero-tail (blocks [0, zTail) zero zbuf[zN] floats)
__global__ void e2v_finish_kernel(const u16* __restrict__ Y,
                                  const int* __restrict__ noff,
                                  const int* __restrict__ node_e,
                                  const u16* __restrict__ Xinit,
                                  u16* __restrict__ H, int N,
                                  float* __restrict__ zbuf, int zN, int zTail)
{
    if ((int)blockIdx.x < zTail) {
        int id = (int)blockIdx.x * 256 + (int)threadIdx.x;
        if (id < zN) zbuf[id] = 0.f;
        return;
    }
    int v = ((int)blockIdx.x - zTail) * 8 + (threadIdx.x >> 5);
    if (v >= N) return;
    int sl = threadIdx.x & 31;
    int col = sl * 8;
    int i0 = noff[v], i1 = noff[v + 1];
    float acc[8] = {0.f, 0.f, 0.f, 0.f, 0.f, 0.f, 0.f, 0.f};
    int i = i0;
    for (; i + 3 < i1; i += 4) {
        int e0 = node_e[i + 0], e1 = node_e[i + 1], e2 = node_e[i + 2], e3 = node_e[i + 3];
        u16x8 r0 = *(const u16x8*)(Y + (size_t)e0 * 256 + col);
        u16x8 r1 = *(const u16x8*)(Y + (size_t)e1 * 256 + col);
        u16x8 r2 = *(const u16x8*)(Y + (size_t)e2 * 256 + col);
        u16x8 r3 = *(const u16x8*)(Y + (size_t)e3 * 256 + col);
#pragma unroll
        for (int q = 0; q < 8; ++q) {
            acc[q] += h2f(r0[q]);
            acc[q] += h2f(r1[q]);
            acc[q] += h2f(r2[q]);
            acc[q] += h2f(r3[q]);
        }
    }
    for (; i < i1; ++i) {
        int e = node_e[i];
        u16x8 r = *(const u16x8*)(Y + (size_t)e * 256 + col);
#pragma unroll
        for (int q = 0; q < 8; ++q) acc[q] += h2f(r[q]);
    }
    float inv = (i1 > i0) ? 1.0f / (float)(i1 - i0) : 0.f;
    size_t base = (size_t)v * 256 + col;
    u16x8 xi = *(const u16x8*)(Xinit + base);
    u16x8 hv;
#pragma unroll
    for (int q = 0; q < 8; ++q) {
        float mm = acc[q] * inv;
        float oq = (mm > 0.f ? mm : expm1f(mm)) + h2f(xi[q]);
        hv[q] = f2h(oq);
    }
    *(u16x8*)(H + base) = hv;
}

// =============== hyperconv ===============
__global__ void yh_kernel(const u16* __restrict__ Xc,
                          const int* __restrict__ eoff, const int* __restrict__ edge_v,
                          const int* __restrict__ noff, u16* __restrict__ Yh, int M)
{
    int e = blockIdx.x * 16 + (threadIdx.x >> 4);
    if (e >= M) return;
    int sl = threadIdx.x & 15;
    int col = sl * 8;
    int j0 = eoff[e], j1 = eoff[e + 1];

    float dsum = 0.f;
    for (int j = j0 + sl; j < j1; j += 16) {
        int v = edge_v[j];
        dsum += (float)(noff[v + 1] - noff[v]);
    }
#pragma unroll
    for (int o = 8; o; o >>= 1) dsum += __shfl_xor(dsum, o);
    float De = dsum / ((float)(j1 - j0) + 1.0f);
    float deinv = De > 0.f ? rsqrtf(De) : 1.0f;

    float acc[8] = {0.f, 0.f, 0.f, 0.f, 0.f, 0.f, 0.f, 0.f};
    int j = j0;
    for (; j + 3 < j1; j += 4) {
        int v0 = edge_v[j + 0], v1 = edge_v[j + 1], v2 = edge_v[j + 2], v3 = edge_v[j + 3];
        u16x8 r0 = *(const u16x8*)(Xc + (size_t)v0 * 128 + col);
        u16x8 r1 = *(const u16x8*)(Xc + (size_t)v1 * 128 + col);
        u16x8 r2 = *(const u16x8*)(Xc + (size_t)v2 * 128 + col);
        u16x8 r3 = *(const u16x8*)(Xc + (size_t)v3 * 128 + col);
#pragma unroll
        for (int q = 0; q < 8; ++q) {
            acc[q] += h2f(r0[q]);
            acc[q] += h2f(r1[q]);
            acc[q] += h2f(r2[q]);
            acc[q] += h2f(r3[q]);
        }
    }
    for (; j < j1; ++j) {
        int v = edge_v[j];
        u16x8 r = *(const u16x8*)(Xc + (size_t)v * 128 + col);
#pragma unroll
        for (int q = 0; q < 8; ++q) acc[q] += h2f(r[q]);
    }
    float sc = ((j1 > j0) ? 1.0f / (float)(j1 - j0) : 0.f) * deinv;
    u16x8 o8;
#pragma unroll
    for (int q = 0; q < 8; ++q) o8[q] = f2h(acc[q] * sc);
    *(u16x8*)(Yh + (size_t)e * 128 + col) = o8;
}

__global__ void xo_final_kernel(const u16* __restrict__ Yh,
                                const int* __restrict__ noff, const int* __restrict__ node_e,
                                float* __restrict__ out, int N)
{
    int v = blockIdx.x * 16 + (threadIdx.x >> 4);
    if (v >= N) return;
    int sl = threadIdx.x & 15;
    int col = sl * 8;
    int i0 = noff[v], i1 = noff[v + 1];
    float acc[8] = {0.f, 0.f, 0.f, 0.f, 0.f, 0.f, 0.f, 0.f};
    int i = i0;
    for (; i + 3 < i1; i += 4) {
        int e0 = node_e[i + 0], e1 = node_e[i + 1], e2 = node_e[i + 2], e3 = node_e[i + 3];
        u16x8 r0 = *(const u16x8*)(Yh + (size_t)e0 * 128 + col);
        u16x8 r1 = *(const u16x8*)(Yh + (size_t)e1 * 128 + col);
        u16x8 r2 = *(const u16x8*)(Yh + (size_t)e2 * 128 + col);
        u16x8 r3 = *(const u16x8*)(Yh + (size_t)e3 * 128 + col);
#pragma unroll
        for (int q = 0; q < 8; ++q) {
            acc[q] += h2f(r0[q]);
            acc[q] += h2f(r1[q]);
            acc[q] += h2f(r2[q]);
            acc[q] += h2f(r3[q]);
        }
    }
    for (; i < i1; ++i) {
        int e = node_e[i];
        u16x8 r = *(const u16x8*)(Yh + (size_t)e * 128 + col);
#pragma unroll
        for (int q = 0; q < 8; ++q) acc[q] += h2f(r[q]);
    }
    float sc = (i1 > i0) ? rsqrtf((float)(i1 - i0)) : 0.f;
    float4 oA, oB;
    oA.x = acc[0] * sc; oA.y = acc[1] * sc; oA.z = acc[2] * sc; oA.w = acc[3] * sc;
    oB.x = acc[4] * sc; oB.y = acc[5] * sc; oB.z = acc[6] * sc; oB.w = acc[7] * sc;
    float* d = out + (size_t)v * 128 + col;
    *(float4*)d = oA;
    *(float4*)(d + 4) = oB;
}

// =============== host-side ===============
static void gemm128(const u16* A, int lda,
                    const u16* B, int ldb,
                    const float* biasF, const float* biasB,
                    u16* CbA, u16* CbB,
                    const float* avec, float* scoreOut,
                    const int* cV, const int* cE, int* ecnt, int* ncnt,
                    int* rankE, int* rankN, int tNnz,
                    int M, int Nc, int ncSplit, int K,
                    hipStream_t stream)
{
    int nrb = (M + 127) / 128, ncb = Nc / 128;
    int nrb8 = ((nrb + 7) / 8) * 8;
    int nGemm = nrb8 * ncb;
    int nCnt = (cV != nullptr) ? (tNnz + 2047) / 2048 : 0;
    int T = nGemm + nCnt;
    int sStride = nCnt ? max(T / nCnt, 1) : 1;
    gemm_mfma128_kernel<<<T, 256, 0, stream>>>(
        A, lda, B, ldb, biasF, biasB, CbA, CbB, avec, scoreOut,
        cV, cE, ecnt, ncnt, rankE, rankN, tNnz, nCnt, sStride,
        M, Nc, ncSplit, K, nrb, ncb);
}

static void gemm64(const u16* A, int lda,
                   const u16* B, int ldb,
                   const float* biasF, const float* biasB,
                   u16* CbA, u16* CbB,
                   const float* avec, float* scoreOut,
                   int M, int Nc, int ncSplit, int K,
                   hipStream_t stream)
{
    int nrb = (M + 127) / 128, ncb = Nc / 64;
    int nrb8 = ((nrb + 7) / 8) * 8;
    gemm_mfma64_kernel<<<nrb8 * ncb, 256, 0, stream>>>(
        A, lda, B, ldb, biasF, biasB, CbA, CbB, avec, scoreOut,
        M, Nc, ncSplit, K, nrb, ncb);
}

extern "C" void kernel_launch(void* const* d_in, const int* in_sizes, int n_in,
                              void* d_out, int out_size, void* d_ws, size_t ws_size,
                              hipStream_t stream)
{
    const float* X   = (const float*)d_in[0];
    const int*   V   = (const int*)d_in[1];
    const int*   E   = (const int*)d_in[2];
    const float* S   = (const float*)d_in[3];
    const float* Wx0 = (const float*)d_in[4];  const float* bx0 = (const float*)d_in[5];
    const float* Wv0 = (const float*)d_in[6];  const float* bv0 = (const float*)d_in[7];
    const float* a0  = (const float*)d_in[8];
    const float* Wt0 = (const float*)d_in[9];  const float* bt0 = (const float*)d_in[10];
    const float* Wx1 = (const float*)d_in[11]; const float* bx1 = (const float*)d_in[12];
    const float* Wv1 = (const float*)d_in[13]; const float* bv1 = (const float*)d_in[14];
    const float* a1  = (const float*)d_in[15];
    const float* Wt1 = (const float*)d_in[16]; const float* bt1 = (const float*)d_in[17];
    const float* Wf  = (const float*)d_in[18]; const float* bf  = (const float*)d_in[19];

    int N   = in_sizes[0] / 128;
    int NNZ = in_sizes[1];
    int M   = in_sizes[3] / 64;

    float* ws = (float*)d_ws;
    size_t off = 0;
    u16* XinitB = (u16*)(ws + off); off += (size_t)N * 128;  // [N,256] f16; also Yh [M,128] f16
    u16* XfeatR = (u16*)(ws + off); off += (size_t)N * 128;  // Xfeatb/Ybufb/Xcb
    u16* Xfeatb = XfeatR;
    u16* Ybufb  = XfeatR;
    u16* Abuf = (u16*)(ws + off); off += (size_t)N * 128;    // [N,256] f16: X cast / h
    u16* Ae   = (u16*)(ws + off); off += (size_t)M * 160;    // [M,320] f16 edge buffer
    u16* WxvT0 = (u16*)(ws + off); off += (size_t)(512 * 128) / 2;
    u16* WtT0  = (u16*)(ws + off); off += (size_t)(256 * 320) / 2;
    u16* WxvT1 = (u16*)(ws + off); off += (size_t)(512 * 256) / 2;
    u16* WtT1  = (u16*)(ws + off); off += (size_t)(256 * 320) / 2;
    u16* WfT   = (u16*)(ws + off); off += (size_t)(128 * 256) / 2;
    // ecnt | ncnt | score contiguous -> one zero pass covers all three
    int* ecnt   = (int*)(ws + off); off += (size_t)M;
    int* ncnt   = (int*)(ws + off); off += (size_t)N;
    float* score = ws + off;        off += (size_t)N;
    int* eoff   = (int*)(ws + off); off += (size_t)(M + 1);
    int* psumE  = (int*)(ws + off); off += 64;
    int* edge_v = (int*)(ws + off); off += (size_t)NNZ;
    int* noff   = (int*)(ws + off); off += (size_t)(N + 1);
    int* psumN  = (int*)(ws + off); off += 64;
    int* node_e = (int*)(ws + off); off += (size_t)NNZ;
    int* rankE  = (int*)(ws + off); off += (size_t)NNZ;
    int* rankN  = (int*)(ws + off); off += (size_t)NNZ;

    // ---- fused prep: zero (ecnt|ncnt|score) + input casts + weight casts ----
    int n4x = N * 128 / 4, nS = M * 64;
    int zN4 = (M + 2 * N) / 4;                 // M, N multiples of 4 here
    int nbZero = (zN4 + 255) / 256;
    int nbCast = (n4x + nS + 255) / 256;
    WJobs jobs;
    jobs.j[0] = {Wx0, WxvT0,             128, 8};
    jobs.j[1] = {Wv0, WxvT0 + 256 * 128, 128, 8};
    jobs.j[2] = {Wt0, WtT0,              320, 8};
    jobs.j[3] = {Wx1, WxvT1,             256, 8};
    jobs.j[4] = {Wv1, WxvT1 + 256 * 256, 256, 8};
    jobs.j[5] = {Wt1, WtT1,              320, 8};
    jobs.j[6] = {Wf,  WfT,               256, 7};
    int nbW = 7 * 320;
    prep_fused_kernel<<<nbZero + nbCast + nbW, 256, 0, stream>>>(
        ecnt, zN4, nbZero, X, Abuf, n4x, S, Ae, nS, nbCast, jobs);

    // ---- layer 0 X-GEMM (128x128) carries dispersed count blocks ----
    gemm128(Abuf, 128, WxvT0, 128, bx0, bv0, XinitB, Xfeatb, a0, score,
            V, E, ecnt, ncnt, rankE, rankN, NNZ, N, 512, 256, 128, stream);

    // ---- scans (exclusive offsets from counts) ----
    int nbE = (M + 1023) / 1024, nbN = (N + 1023) / 1024;
    scan_part1_dual<<<nbE + nbN, 256, 0, stream>>>(ecnt, eoff, psumE, M, nbE,
                                                   ncnt, noff, psumN, N);
    scan_part2_dual<<<nbE + nbN, 256, 0, stream>>>(eoff, psumE, M, nbE,
                                                   noff, psumN, N);

    // ---- atomic-free CSR fill (both edge_v and node_e) ----
    fill_ranked_kernel<<<((NNZ + 3) / 4 + 255) / 256, 256, 0, stream>>>(
        V, E, rankE, rankN, eoff, noff, edge_v, node_e, NNZ);

    // ---- layer 0 rest ----
    v2e_fused_kernel<<<(M + 7) / 8, 256, 0, stream>>>(Xfeatb, score, eoff, edge_v, Ae, M);
    gemm64(Ae, 320, WtT0, 320, nullptr, bt0, nullptr, Ybufb, nullptr, nullptr,
           M, 256, 0, 320, stream);
    {   // e2v + zero score for layer 1
        int zTail = (N + 255) / 256;
        e2v_finish_kernel<<<zTail + (N + 7) / 8, 256, 0, stream>>>(
            Ybufb, noff, node_e, XinitB, Abuf, N, score, N, zTail);
    }

    // ---- layer 1 ----
    gemm128(Abuf, 256, WxvT1, 256, bx1, bv1, XinitB, Xfeatb, a1, score,
            nullptr, nullptr, nullptr, nullptr, nullptr, nullptr, 0,
            N, 512, 256, 256, stream);
    v2e_fused_kernel<<<(M + 7) / 8, 256, 0, stream>>>(Xfeatb, score, eoff, edge_v, Ae, M);
    gemm64(Ae, 320, WtT1, 320, nullptr, bt1, nullptr, Ybufb, nullptr, nullptr,
           M, 256, 0, 320, stream);
    e2v_finish_kernel<<<(N + 7) / 8, 256, 0, stream>>>(
        Ybufb, noff, node_e, XinitB, Abuf, N, nullptr, 0, 0);

    // ---- hyperconv (all-f16 intermediates, fp32 final out) ----
    u16* Xcb = XfeatR;   // [N,128] f16
    u16* Yhb = XinitB;   // [M,128] f16
    gemm64(Abuf, 256, WfT, 256, bf, nullptr, Xcb, nullptr, nullptr, nullptr,
           N, 128, 128, 256, stream);
    yh_kernel<<<(M + 15) / 16, 256, 0, stream>>>(Xcb, eoff, edge_v, noff, Yhb, M);
    xo_final_kernel<<<(N + 15) / 16, 256, 0, stream>>>(Yhb, noff, node_e, (float*)d_out, N);
}